// Round 9
// baseline (93.448 us; speedup 1.0000x reference)
//
#include <hip/hip_runtime.h>

#define L  512
#define F  64
#define P  32
#define ZO 128
#define JCH 16   // j-chunk for k_T

constexpr float EPS_LN   = 1e-10f;
constexpr float EPS_NORM = 1e-3f;

typedef float f32x2 __attribute__((ext_vector_type(2)));

// ---------------------------------------------------------------------------
// Kernel 1: LayerNorm over F, then a = (y@Wa^T + ba)*mask, b = (y@Wb^T + bb)*mask
// One wave per row (F == 64 == wave size). 4 rows per block. (~2us, frozen)
// ---------------------------------------------------------------------------
__global__ __launch_bounds__(256) void k_ln_proj(
    const float* __restrict__ M, const float* __restrict__ mask,
    const float* __restrict__ gamma, const float* __restrict__ beta,
    const float* __restrict__ Wa, const float* __restrict__ ba,
    const float* __restrict__ Wb, const float* __restrict__ bb,
    float* __restrict__ a, float* __restrict__ b) {
  __shared__ float y_lds[4][F];
  const int wave = threadIdx.x >> 6;
  const int lane = threadIdx.x & 63;
  const int row  = blockIdx.x * 4 + wave;

  float m = M[row * F + lane];
  float s = m;
  #pragma unroll
  for (int o = 32; o >= 1; o >>= 1) s += __shfl_xor(s, o);
  float mean = s * (1.0f / F);
  float d = m - mean;
  float v = d * d;
  #pragma unroll
  for (int o = 32; o >= 1; o >>= 1) v += __shfl_xor(v, o);
  float rstd = rsqrtf(v * (1.0f / F) + EPS_LN);
  float y = d * rstd * gamma[lane] + beta[lane];
  y_lds[wave][lane] = y;
  __syncthreads();

  const float mk = mask[row];
  const float* W    = (lane < P) ? Wa : Wb;
  const float* bias = (lane < P) ? ba : bb;
  const int p = lane & (P - 1);
  float acc = 0.f;
  #pragma unroll 8
  for (int f = 0; f < F; ++f) acc += y_lds[wave][f] * W[p * F + f];
  acc = (acc + bias[p]) * mk;
  float* outp = (lane < P) ? a : b;
  outp[row * P + p] = acc;
}

// ---------------------------------------------------------------------------
// Kernel 2: T[j][z][d] = sum_e b[j][e] * Wz[z*1024 + d*32 + e]
// (R5 form, ~4-6us, frozen.)
// ---------------------------------------------------------------------------
__global__ __launch_bounds__(256) void k_T(
    const float* __restrict__ b, const float* __restrict__ Wz,
    float* __restrict__ T) {
  const int seg = blockIdx.x * 256 + threadIdx.x;   // 0..4095
  const int j0  = blockIdx.y * JCH;

  float4 w[8];
  const float4* wp = (const float4*)(Wz + (size_t)seg * 32);
  #pragma unroll
  for (int q = 0; q < 8; ++q) w[q] = wp[q];

  #pragma unroll 2
  for (int jj = 0; jj < JCH; ++jj) {
    const float* __restrict__ br = b + (size_t)(j0 + jj) * P;  // uniform
    float acc0 = 0.f, acc1 = 0.f, acc2 = 0.f, acc3 = 0.f;
    #pragma unroll
    for (int q = 0; q < 8; ++q) {
      acc0 += w[q].x * br[q * 4 + 0];
      acc1 += w[q].y * br[q * 4 + 1];
      acc2 += w[q].z * br[q * 4 + 2];
      acc3 += w[q].w * br[q * 4 + 3];
    }
    T[(size_t)(j0 + jj) * (ZO * P) + seg] = (acc0 + acc1) + (acc2 + acc3);
  }
}

// ---------------------------------------------------------------------------
// Kernel 3: Z[i,j,z] = (sum_d a[i,d]*T[j,z,d] + bz[z]) / (eps + mask_i*mask_j)
// Round-9 change: ONE BLOCK PER j (grid=512). All 4 waves of the block use
// the SAME 16 KB T[j] fragment (wave 0's fetch seeds L1/L2; waves 1-3 hit)
// and split the full i-range into 4x128 contiguous chunks. T HBM/L3 traffic
// drops 134 MB -> 8 MB (the R4-R8 hidden cost: T was re-fetched once per
// i-chunk, 16x). a (64 KB) is L2-resident. Keeps R8's double-buffered
// a-row pipeline and f32x2 nontemporal 512-B/wave stores.
// ---------------------------------------------------------------------------
__global__ __launch_bounds__(256) void k_z(
    const float* __restrict__ a, const float* __restrict__ mask,
    const float* __restrict__ T, const float* __restrict__ bz,
    float* __restrict__ Z) {
  const int t  = threadIdx.x;
  const int l  = t & 63;          // lane: z-pair index (z = 2l, 2l+1)
  const int w  = t >> 6;          // wave index -> i-chunk of 128 rows
  const int j  = blockIdx.x;
  const int i0 = w * 128;

  // T fragment: rows z=2l and z=2l+1 of T[j] -> 64 consecutive floats
  float4 tw[16];
  const float4* tp = (const float4*)(T + ((size_t)j * ZO + 2 * l) * P);
  #pragma unroll
  for (int q = 0; q < 16; ++q) tw[q] = tp[q];

  const float bzx = bz[2 * l], bzy = bz[2 * l + 1];
  const float mj  = mask[j];      // wave-uniform

  const float* __restrict__ abase = a + (size_t)i0 * P;
  float* outbase = Z + ((size_t)i0 * L + j) * ZO + 2 * l;

  auto body = [&](const float4* areg, int irow) {
    float x0 = 0.f, x1 = 0.f, x2 = 0.f, x3 = 0.f;
    float y0 = 0.f, y1 = 0.f, y2 = 0.f, y3 = 0.f;
    #pragma unroll
    for (int q = 0; q < 8; ++q) {
      float4 av = areg[q];
      x0 += av.x * tw[q].x;      x1 += av.y * tw[q].y;
      x2 += av.z * tw[q].z;      x3 += av.w * tw[q].w;
      y0 += av.x * tw[8 + q].x;  y1 += av.y * tw[8 + q].y;
      y2 += av.z * tw[8 + q].z;  y3 += av.w * tw[8 + q].w;
    }
    const float inv = 1.0f / (EPS_NORM + mask[i0 + irow] * mj);
    f32x2 o;
    o.x = ((x0 + x1) + (x2 + x3) + bzx) * inv;
    o.y = ((y0 + y1) + (y2 + y3) + bzy) * inv;
    __builtin_nontemporal_store(o, (f32x2*)(outbase + (size_t)irow * (L * ZO)));
  };

  float4 a0[8], a1[8];
  #pragma unroll
  for (int q = 0; q < 8; ++q) a0[q] = ((const float4*)abase)[q];

  for (int i = 0; i < 128; i += 2) {
    #pragma unroll
    for (int q = 0; q < 8; ++q)
      a1[q] = ((const float4*)(abase + (size_t)(i + 1) * P))[q];
    body(a0, i);
    const int inx = (i + 2 < 128) ? (i + 2) : 0;
    #pragma unroll
    for (int q = 0; q < 8; ++q)
      a0[q] = ((const float4*)(abase + (size_t)inx * P))[q];
    body(a1, i + 1);
  }
}

// ---------------------------------------------------------------------------
extern "C" void kernel_launch(void* const* d_in, const int* in_sizes, int n_in,
                              void* d_out, int out_size, void* d_ws, size_t ws_size,
                              hipStream_t stream) {
  const float* M     = (const float*)d_in[0];
  const float* mask  = (const float*)d_in[1];
  const float* gamma = (const float*)d_in[2];
  const float* beta  = (const float*)d_in[3];
  const float* Wa    = (const float*)d_in[4];
  const float* ba    = (const float*)d_in[5];
  const float* Wb    = (const float*)d_in[6];
  const float* bb    = (const float*)d_in[7];
  const float* Wz    = (const float*)d_in[8];
  const float* bz    = (const float*)d_in[9];

  float* Z = (float*)d_out;
  float* a = (float*)d_ws;            // 512*32 f32 = 64 KB
  float* b = a + L * P;               // 64 KB
  float* T = b + L * P;               // 8 MB

  k_ln_proj<<<L / 4, 256, 0, stream>>>(M, mask, gamma, beta, Wa, ba, Wb, bb, a, b);
  k_T<<<dim3((ZO * P) / 256, L / JCH), 256, 0, stream>>>(b, Wz, T);
  k_z<<<L, 256, 0, stream>>>(a, mask, T, bz, Z);
}

// Round 10
// 76.684 us; speedup vs baseline: 1.2186x; 1.2186x over previous
//
#include <hip/hip_runtime.h>

#define L  512
#define F  64
#define P  32
#define ZO 128
#define ICH 32   // i-chunk for k_z (shared by the block's 4 waves)
#define JCH 16   // j-chunk for k_T

constexpr float EPS_LN   = 1e-10f;
constexpr float EPS_NORM = 1e-3f;

typedef float f32x2 __attribute__((ext_vector_type(2)));

// ---------------------------------------------------------------------------
// Kernel 1: LayerNorm over F, then a = (y@Wa^T + ba)*mask, b = (y@Wb^T + bb)*mask
// One wave per row (F == 64 == wave size). 4 rows per block. (~2us, frozen)
// ---------------------------------------------------------------------------
__global__ __launch_bounds__(256) void k_ln_proj(
    const float* __restrict__ M, const float* __restrict__ mask,
    const float* __restrict__ gamma, const float* __restrict__ beta,
    const float* __restrict__ Wa, const float* __restrict__ ba,
    const float* __restrict__ Wb, const float* __restrict__ bb,
    float* __restrict__ a, float* __restrict__ b) {
  __shared__ float y_lds[4][F];
  const int wave = threadIdx.x >> 6;
  const int lane = threadIdx.x & 63;
  const int row  = blockIdx.x * 4 + wave;

  float m = M[row * F + lane];
  float s = m;
  #pragma unroll
  for (int o = 32; o >= 1; o >>= 1) s += __shfl_xor(s, o);
  float mean = s * (1.0f / F);
  float d = m - mean;
  float v = d * d;
  #pragma unroll
  for (int o = 32; o >= 1; o >>= 1) v += __shfl_xor(v, o);
  float rstd = rsqrtf(v * (1.0f / F) + EPS_LN);
  float y = d * rstd * gamma[lane] + beta[lane];
  y_lds[wave][lane] = y;
  __syncthreads();

  const float mk = mask[row];
  const float* W    = (lane < P) ? Wa : Wb;
  const float* bias = (lane < P) ? ba : bb;
  const int p = lane & (P - 1);
  float acc = 0.f;
  #pragma unroll 8
  for (int f = 0; f < F; ++f) acc += y_lds[wave][f] * W[p * F + f];
  acc = (acc + bias[p]) * mk;
  float* outp = (lane < P) ? a : b;
  outp[row * P + p] = acc;
}

// ---------------------------------------------------------------------------
// Kernel 2: T[j][z][d] = sum_e b[j][e] * Wz[z*1024 + d*32 + e]
// (R5 form, ~4-6us, frozen.)
// ---------------------------------------------------------------------------
__global__ __launch_bounds__(256) void k_T(
    const float* __restrict__ b, const float* __restrict__ Wz,
    float* __restrict__ T) {
  const int seg = blockIdx.x * 256 + threadIdx.x;   // 0..4095
  const int j0  = blockIdx.y * JCH;

  float4 w[8];
  const float4* wp = (const float4*)(Wz + (size_t)seg * 32);
  #pragma unroll
  for (int q = 0; q < 8; ++q) w[q] = wp[q];

  #pragma unroll 2
  for (int jj = 0; jj < JCH; ++jj) {
    const float* __restrict__ br = b + (size_t)(j0 + jj) * P;  // uniform
    float acc0 = 0.f, acc1 = 0.f, acc2 = 0.f, acc3 = 0.f;
    #pragma unroll
    for (int q = 0; q < 8; ++q) {
      acc0 += w[q].x * br[q * 4 + 0];
      acc1 += w[q].y * br[q * 4 + 1];
      acc2 += w[q].z * br[q * 4 + 2];
      acc3 += w[q].w * br[q * 4 + 3];
    }
    T[(size_t)(j0 + jj) * (ZO * P) + seg] = (acc0 + acc1) + (acc2 + acc3);
  }
}

// ---------------------------------------------------------------------------
// Kernel 3: Z[i,j,z] = (sum_d a[i,d]*T[j,z,d] + bz[z]) / (eps + mask_i*mask_j)
// Round-10: R9 counters showed k_z is STALL-bound (1.65 TB/s, VALU 28.6%),
// not traffic-bound (FETCH 4.4MB). Fixes:
//  - a-chunk + mask staged in LDS, shared by all 4 waves: per-iter a-reads
//    are ds_read_b128 broadcast on lgkmcnt -> decoupled from the store
//    vmcnt FIFO (R9's vector a-loads queued behind backpressured stores).
//  - plain (cached) stores, NOT nontemporal: L2 absorbs store bursts.
//  - R8's proven grid shape: 2048 blocks = 8/CU (occupancy is the one
//    lever that measurably moved k_z: 46us @ 8 blk/CU vs 84us @ 2).
//  - __builtin_amdgcn_rcpf instead of exact divide.
// LDS pipe/iter: 8 x ds_read_b128 = ~96cyc < 128cyc of FMA issue -> VALU-bound.
// ---------------------------------------------------------------------------
__global__ __launch_bounds__(256) void k_z(
    const float* __restrict__ a, const float* __restrict__ mask,
    const float* __restrict__ T, const float* __restrict__ bz,
    float* __restrict__ Z) {
  __shared__ float a_lds[ICH * P];   // 4 KB
  __shared__ float mi_lds[ICH];      // 128 B
  const int t  = threadIdx.x;
  const int l  = t & 63;          // lane: z-pair (z = 2l, 2l+1)
  const int w  = t >> 6;          // wave -> j offset within block
  const int j  = blockIdx.x * 4 + w;
  const int i0 = blockIdx.y * ICH;

  // stage a-chunk (one float4 per thread, single coalesced instr) + mask
  ((float4*)a_lds)[t] = ((const float4*)(a + (size_t)i0 * P))[t];
  if (t < ICH) mi_lds[t] = mask[i0 + t];
  __syncthreads();

  // T fragment: rows z=2l, 2l+1 of T[j] -> 64 consecutive floats (16 float4)
  float4 tw[16];
  const float4* tp = (const float4*)(T + ((size_t)j * ZO + 2 * l) * P);
  #pragma unroll
  for (int q = 0; q < 16; ++q) tw[q] = tp[q];

  const float bzx = bz[2 * l], bzy = bz[2 * l + 1];
  const float mj  = mask[j];      // wave-uniform

  float* outbase = Z + ((size_t)i0 * L + j) * ZO + 2 * l;

  #pragma unroll 2
  for (int i = 0; i < ICH; ++i) {
    const float4* ai = (const float4*)(a_lds + i * P);  // broadcast ds_read
    float x0 = 0.f, x1 = 0.f, x2 = 0.f, x3 = 0.f;
    float y0 = 0.f, y1 = 0.f, y2 = 0.f, y3 = 0.f;
    #pragma unroll
    for (int q = 0; q < 8; ++q) {
      float4 av = ai[q];
      x0 += av.x * tw[q].x;      x1 += av.y * tw[q].y;
      x2 += av.z * tw[q].z;      x3 += av.w * tw[q].w;
      y0 += av.x * tw[8 + q].x;  y1 += av.y * tw[8 + q].y;
      y2 += av.z * tw[8 + q].z;  y3 += av.w * tw[8 + q].w;
    }
    const float inv = __builtin_amdgcn_rcpf(EPS_NORM + mi_lds[i] * mj);
    f32x2 o;
    o.x = ((x0 + x1) + (x2 + x3) + bzx) * inv;
    o.y = ((y0 + y1) + (y2 + y3) + bzy) * inv;
    *(f32x2*)(outbase + (size_t)i * (L * ZO)) = o;
  }
}

// ---------------------------------------------------------------------------
extern "C" void kernel_launch(void* const* d_in, const int* in_sizes, int n_in,
                              void* d_out, int out_size, void* d_ws, size_t ws_size,
                              hipStream_t stream) {
  const float* M     = (const float*)d_in[0];
  const float* mask  = (const float*)d_in[1];
  const float* gamma = (const float*)d_in[2];
  const float* beta  = (const float*)d_in[3];
  const float* Wa    = (const float*)d_in[4];
  const float* ba    = (const float*)d_in[5];
  const float* Wb    = (const float*)d_in[6];
  const float* bb    = (const float*)d_in[7];
  const float* Wz    = (const float*)d_in[8];
  const float* bz    = (const float*)d_in[9];

  float* Z = (float*)d_out;
  float* a = (float*)d_ws;            // 512*32 f32 = 64 KB
  float* b = a + L * P;               // 64 KB
  float* T = b + L * P;               // 8 MB

  k_ln_proj<<<L / 4, 256, 0, stream>>>(M, mask, gamma, beta, Wa, ba, Wb, bb, a, b);
  k_T<<<dim3((ZO * P) / 256, L / JCH), 256, 0, stream>>>(b, Wz, T);
  k_z<<<dim3(L / 4, L / ICH), 256, 0, stream>>>(a, mask, T, bz, Z);
}

// Round 11
// 64.154 us; speedup vs baseline: 1.4566x; 1.1953x over previous
//
#include <hip/hip_runtime.h>

#define L  512
#define F  64
#define P  32
#define ZO 128
#define JCH 16   // j-chunk for k_T

constexpr float EPS_LN   = 1e-10f;
constexpr float EPS_NORM = 1e-3f;

typedef float f32x2 __attribute__((ext_vector_type(2)));
typedef float sf16  __attribute__((ext_vector_type(16)));

// ---------------------------------------------------------------------------
// Kernel 1: LayerNorm + two 64->32 projections. (~2us, frozen)
// ---------------------------------------------------------------------------
__global__ __launch_bounds__(256) void k_ln_proj(
    const float* __restrict__ M, const float* __restrict__ mask,
    const float* __restrict__ gamma, const float* __restrict__ beta,
    const float* __restrict__ Wa, const float* __restrict__ ba,
    const float* __restrict__ Wb, const float* __restrict__ bb,
    float* __restrict__ a, float* __restrict__ b) {
  __shared__ float y_lds[4][F];
  const int wave = threadIdx.x >> 6;
  const int lane = threadIdx.x & 63;
  const int row  = blockIdx.x * 4 + wave;

  float m = M[row * F + lane];
  float s = m;
  #pragma unroll
  for (int o = 32; o >= 1; o >>= 1) s += __shfl_xor(s, o);
  float mean = s * (1.0f / F);
  float d = m - mean;
  float v = d * d;
  #pragma unroll
  for (int o = 32; o >= 1; o >>= 1) v += __shfl_xor(v, o);
  float rstd = rsqrtf(v * (1.0f / F) + EPS_LN);
  float y = d * rstd * gamma[lane] + beta[lane];
  y_lds[wave][lane] = y;
  __syncthreads();

  const float mk = mask[row];
  const float* W    = (lane < P) ? Wa : Wb;
  const float* bias = (lane < P) ? ba : bb;
  const int p = lane & (P - 1);
  float acc = 0.f;
  #pragma unroll 8
  for (int f = 0; f < F; ++f) acc += y_lds[wave][f] * W[p * F + f];
  acc = (acc + bias[p]) * mk;
  float* outp = (lane < P) ? a : b;
  outp[row * P + p] = acc;
}

// ---------------------------------------------------------------------------
// Kernel 2: T[j][z][d] = sum_e b[j][e] * Wz[z*1024 + d*32 + e]  (~5us, frozen)
// ---------------------------------------------------------------------------
__global__ __launch_bounds__(256) void k_T(
    const float* __restrict__ b, const float* __restrict__ Wz,
    float* __restrict__ T) {
  const int seg = blockIdx.x * 256 + threadIdx.x;   // 0..4095
  const int j0  = blockIdx.y * JCH;

  float4 w[8];
  const float4* wp = (const float4*)(Wz + (size_t)seg * 32);
  #pragma unroll
  for (int q = 0; q < 8; ++q) w[q] = wp[q];

  #pragma unroll 2
  for (int jj = 0; jj < JCH; ++jj) {
    const float* __restrict__ br = b + (size_t)(j0 + jj) * P;  // uniform
    float acc0 = 0.f, acc1 = 0.f, acc2 = 0.f, acc3 = 0.f;
    #pragma unroll
    for (int q = 0; q < 8; ++q) {
      acc0 += w[q].x * br[q * 4 + 0];
      acc1 += w[q].y * br[q * 4 + 1];
      acc2 += w[q].z * br[q * 4 + 2];
      acc3 += w[q].w * br[q * 4 + 3];
    }
    T[(size_t)(j0 + jj) * (ZO * P) + seg] = (acc0 + acc1) + (acc2 + acc3);
  }
}

// ---------------------------------------------------------------------------
// Kernel 3: Z[i,j,z] = (sum_d a[i,d]*T[j,z,d] + bz[z]) / (eps + mask_i*mask_j)
// Round-11: R9/R10 showed k_z is stall-bound, not traffic-bound; LDS path is
// pipe-bound (R10). New: a-row + mask[i] fetched via inline-asm s_load into
// SGPRs (scalar pipe, lgkmcnt) -> the vmem FIFO carries ONLY the NT output
// stores, so load-waits never queue behind store backpressure (R9 disease).
// Software-pipelined depth-1: wait(cur) -> prefetch(next) -> 64 v_fmac(v,s,v).
// Ordering is SSA-enforced: the waitcnt asm pass-throughs ("+s") the loaded
// tuples, so FMAs data-depend on the wait. Bijective XCD swizzle gives each
// XCD a contiguous ~16MB write window (attacks DRAM row thrash @1.65TB/s).
// ---------------------------------------------------------------------------
__global__ __launch_bounds__(256) void k_z(
    const float* __restrict__ a, const float* __restrict__ mask,
    const float* __restrict__ T, const float* __restrict__ bz,
    float* __restrict__ Z) {
  const int t = threadIdx.x;
  const int l = t & 63;           // lane: z-pair (z = 2l, 2l+1)
  const int w = t >> 6;           // wave -> j offset within block
  // bijective XCD swizzle over 2048 blocks (2048 % 8 == 0)
  const int fb = blockIdx.x;
  const int lg = (fb & 7) * 256 + (fb >> 3);
  const int iy = lg >> 7;         // 0..15  i-chunk
  const int jx = lg & 127;        // 0..127 j-group
  const int j  = jx * 4 + w;
  const int i0 = iy * 32;

  // T fragment: rows z=2l, 2l+1 of T[j] -> 64 consecutive floats (16 float4)
  float4 tw[16];
  const float4* tp = (const float4*)(T + ((size_t)j * ZO + 2 * l) * P);
  #pragma unroll
  for (int q = 0; q < 16; ++q) tw[q] = tp[q];

  const float bzx = bz[2 * l], bzy = bz[2 * l + 1];
  const float mj  = mask[j];      // wave-uniform

  const float* abase = a + (size_t)i0 * P;   // block-uniform
  const float* mbase = mask + i0;            // block-uniform
  float* outbase = Z + ((size_t)i0 * L + j) * ZO + 2 * l;

  sf16 loA, hiA, loB, hiB;
  float miA, miB;

#define SPREFETCH(LO, HI, MI, ROW)                                         \
  {                                                                        \
    unsigned offa  = (unsigned)(ROW) * 128u;                               \
    unsigned offa2 = offa + 64u;                                           \
    unsigned offm  = (unsigned)(ROW) * 4u;                                 \
    asm volatile("s_load_dwordx16 %0, %3, %5\n\t"                          \
                 "s_load_dwordx16 %1, %3, %6\n\t"                          \
                 "s_load_dword %2, %4, %7"                                 \
                 : "=&s"(LO), "=&s"(HI), "=&s"(MI)                         \
                 : "s"(abase), "s"(mbase), "s"(offa), "s"(offa2),          \
                   "s"(offm));                                             \
  }
#define SWAIT(LO, HI, MI)                                                  \
  asm volatile("s_waitcnt lgkmcnt(0)" : "+s"(LO), "+s"(HI), "+s"(MI));

  auto body = [&](const sf16& lo, const sf16& hi, float mi, int irow) {
    float x0 = 0.f, x1 = 0.f, x2 = 0.f, x3 = 0.f;
    float y0 = 0.f, y1 = 0.f, y2 = 0.f, y3 = 0.f;
    #pragma unroll
    for (int q = 0; q < 8; ++q) {
      const float e0 = (q < 4) ? lo[4 * q + 0] : hi[4 * q - 16];
      const float e1 = (q < 4) ? lo[4 * q + 1] : hi[4 * q - 15];
      const float e2 = (q < 4) ? lo[4 * q + 2] : hi[4 * q - 14];
      const float e3 = (q < 4) ? lo[4 * q + 3] : hi[4 * q - 13];
      x0 += e0 * tw[q].x;      x1 += e1 * tw[q].y;
      x2 += e2 * tw[q].z;      x3 += e3 * tw[q].w;
      y0 += e0 * tw[8 + q].x;  y1 += e1 * tw[8 + q].y;
      y2 += e2 * tw[8 + q].z;  y3 += e3 * tw[8 + q].w;
    }
    const float inv = __builtin_amdgcn_rcpf(EPS_NORM + mi * mj);
    f32x2 o;
    o.x = ((x0 + x1) + (x2 + x3) + bzx) * inv;
    o.y = ((y0 + y1) + (y2 + y3) + bzy) * inv;
    __builtin_nontemporal_store(o, (f32x2*)(outbase + (size_t)irow * (L * ZO)));
  };

  SPREFETCH(loA, hiA, miA, 0)

  #pragma unroll 1
  for (int i = 0; i < 32; i += 2) {
    SWAIT(loA, hiA, miA)
    SPREFETCH(loB, hiB, miB, i + 1)
    body(loA, hiA, miA, i);
    SWAIT(loB, hiB, miB)
    const int inx = (i + 2 < 32) ? (i + 2) : 0;
    SPREFETCH(loA, hiA, miA, inx)
    body(loB, hiB, miB, i + 1);
  }
#undef SPREFETCH
#undef SWAIT
}

// ---------------------------------------------------------------------------
extern "C" void kernel_launch(void* const* d_in, const int* in_sizes, int n_in,
                              void* d_out, int out_size, void* d_ws, size_t ws_size,
                              hipStream_t stream) {
  const float* M     = (const float*)d_in[0];
  const float* mask  = (const float*)d_in[1];
  const float* gamma = (const float*)d_in[2];
  const float* beta  = (const float*)d_in[3];
  const float* Wa    = (const float*)d_in[4];
  const float* ba    = (const float*)d_in[5];
  const float* Wb    = (const float*)d_in[6];
  const float* bb    = (const float*)d_in[7];
  const float* Wz    = (const float*)d_in[8];
  const float* bz    = (const float*)d_in[9];

  float* Z = (float*)d_out;
  float* a = (float*)d_ws;            // 512*32 f32 = 64 KB
  float* b = a + L * P;               // 64 KB
  float* T = b + L * P;               // 8 MB

  k_ln_proj<<<L / 4, 256, 0, stream>>>(M, mask, gamma, beta, Wa, ba, Wb, bb, a, b);
  k_T<<<dim3((ZO * P) / 256, L / JCH), 256, 0, stream>>>(b, Wz, T);
  k_z<<<2048, 256, 0, stream>>>(a, mask, T, bz, Z);
}

// Round 12
// 63.307 us; speedup vs baseline: 1.4761x; 1.0134x over previous
//
#include <hip/hip_runtime.h>

#define L  512
#define F  64
#define P  32
#define ZO 128
#define ICH 32   // i-chunk for k_z
#define JCH 16   // j-chunk for k_T

constexpr float EPS_LN   = 1e-10f;
constexpr float EPS_NORM = 1e-3f;

typedef float f32x4 __attribute__((ext_vector_type(4)));
typedef float sf16  __attribute__((ext_vector_type(16)));

// ---------------------------------------------------------------------------
// Kernel 1: LayerNorm + two 64->32 projections. (~2us, frozen)
// ---------------------------------------------------------------------------
__global__ __launch_bounds__(256) void k_ln_proj(
    const float* __restrict__ M, const float* __restrict__ mask,
    const float* __restrict__ gamma, const float* __restrict__ beta,
    const float* __restrict__ Wa, const float* __restrict__ ba,
    const float* __restrict__ Wb, const float* __restrict__ bb,
    float* __restrict__ a, float* __restrict__ b) {
  __shared__ float y_lds[4][F];
  const int wave = threadIdx.x >> 6;
  const int lane = threadIdx.x & 63;
  const int row  = blockIdx.x * 4 + wave;

  float m = M[row * F + lane];
  float s = m;
  #pragma unroll
  for (int o = 32; o >= 1; o >>= 1) s += __shfl_xor(s, o);
  float mean = s * (1.0f / F);
  float d = m - mean;
  float v = d * d;
  #pragma unroll
  for (int o = 32; o >= 1; o >>= 1) v += __shfl_xor(v, o);
  float rstd = rsqrtf(v * (1.0f / F) + EPS_LN);
  float y = d * rstd * gamma[lane] + beta[lane];
  y_lds[wave][lane] = y;
  __syncthreads();

  const float mk = mask[row];
  const float* W    = (lane < P) ? Wa : Wb;
  const float* bias = (lane < P) ? ba : bb;
  const int p = lane & (P - 1);
  float acc = 0.f;
  #pragma unroll 8
  for (int f = 0; f < F; ++f) acc += y_lds[wave][f] * W[p * F + f];
  acc = (acc + bias[p]) * mk;
  float* outp = (lane < P) ? a : b;
  outp[row * P + p] = acc;
}

// ---------------------------------------------------------------------------
// Kernel 2: T[j][z][d] = sum_e b[j][e] * Wz[z*1024 + d*32 + e]  (~5us, frozen)
// ---------------------------------------------------------------------------
__global__ __launch_bounds__(256) void k_T(
    const float* __restrict__ b, const float* __restrict__ Wz,
    float* __restrict__ T) {
  const int seg = blockIdx.x * 256 + threadIdx.x;   // 0..4095
  const int j0  = blockIdx.y * JCH;

  float4 w[8];
  const float4* wp = (const float4*)(Wz + (size_t)seg * 32);
  #pragma unroll
  for (int q = 0; q < 8; ++q) w[q] = wp[q];

  #pragma unroll 2
  for (int jj = 0; jj < JCH; ++jj) {
    const float* __restrict__ br = b + (size_t)(j0 + jj) * P;  // uniform
    float acc0 = 0.f, acc1 = 0.f, acc2 = 0.f, acc3 = 0.f;
    #pragma unroll
    for (int q = 0; q < 8; ++q) {
      acc0 += w[q].x * br[q * 4 + 0];
      acc1 += w[q].y * br[q * 4 + 1];
      acc2 += w[q].z * br[q * 4 + 2];
      acc3 += w[q].w * br[q * 4 + 3];
    }
    T[(size_t)(j0 + jj) * (ZO * P) + seg] = (acc0 + acc1) + (acc2 + acc3);
  }
}

// ---------------------------------------------------------------------------
// Kernel 3: Z[i,j,z] = (sum_d a[i,d]*T[j,z,d] + bz[z]) / (eps + mask_i*mask_j)
// Round-12 "z-quad" layout: lane = z-quad (f32x4), wave = 2 consecutive j's
// -> each NT store instr is 1 KB CONTIGUOUS (fillBuffer granularity; R8 was
// 512 B). Block = 8 consecutive j's -> 4 KB write front per i. T fragment =
// 4 z-rows x 32 d = 32 float4 VGPRs. a-row + mask[i] via inline-asm s_load
// into SGPRs (scalar pipe; zero VGPR cost; vmem FIFO = stores only),
// software-pipelined depth-1. launch_bounds(256,3) caps VGPR for 3 w/SIMD.
// ---------------------------------------------------------------------------
__global__ __launch_bounds__(256, 3) void k_z(
    const float* __restrict__ a, const float* __restrict__ mask,
    const float* __restrict__ T, const float* __restrict__ bz,
    float* __restrict__ Z) {
  const int t  = threadIdx.x;
  const int w  = t >> 6;              // wave 0..3
  const int h  = (t >> 5) & 1;        // half-wave -> j offset
  const int zq = t & 31;              // z-quad index
  const int z0 = zq * 4;
  const int j  = blockIdx.x * 8 + 2 * w + h;
  const int i0 = blockIdx.y * ICH;

  // T fragment: rows z0..z0+3 of T[j] -> 128 consecutive floats (32 float4)
  float4 tw[32];
  const float4* tp = (const float4*)(T + ((size_t)j * ZO + z0) * P);
  #pragma unroll
  for (int q = 0; q < 32; ++q) tw[q] = tp[q];

  const float4 bz4 = *(const float4*)(bz + z0);
  const float  mj  = mask[j];         // wave-uniform

  const float* abase = a + (size_t)i0 * P;   // block-uniform
  const float* mbase = mask + i0;            // block-uniform
  float* outbase = Z + ((size_t)i0 * L + j) * ZO + z0;

  sf16 loA, hiA, loB, hiB;
  float miA, miB;

#define SPREFETCH(LO, HI, MI, ROW)                                         \
  {                                                                        \
    unsigned offa  = (unsigned)(ROW) * 128u;                               \
    unsigned offa2 = offa + 64u;                                           \
    unsigned offm  = (unsigned)(ROW) * 4u;                                 \
    asm volatile("s_load_dwordx16 %0, %3, %5\n\t"                          \
                 "s_load_dwordx16 %1, %3, %6\n\t"                          \
                 "s_load_dword %2, %4, %7"                                 \
                 : "=&s"(LO), "=&s"(HI), "=&s"(MI)                         \
                 : "s"(abase), "s"(mbase), "s"(offa), "s"(offa2),          \
                   "s"(offm));                                             \
  }
#define SWAIT(LO, HI, MI)                                                  \
  asm volatile("s_waitcnt lgkmcnt(0)" : "+s"(LO), "+s"(HI), "+s"(MI));

  auto body = [&](const sf16& lo, const sf16& hi, float mi, int irow) {
    float x0 = 0.f, x1 = 0.f, x2 = 0.f, x3 = 0.f;
    #pragma unroll
    for (int q = 0; q < 8; ++q) {
      const float e0 = (q < 4) ? lo[4 * q + 0] : hi[4 * q - 16];
      const float e1 = (q < 4) ? lo[4 * q + 1] : hi[4 * q - 15];
      const float e2 = (q < 4) ? lo[4 * q + 2] : hi[4 * q - 14];
      const float e3 = (q < 4) ? lo[4 * q + 3] : hi[4 * q - 13];
      // z-row c uses tw[c*8+q]; accumulate all 4 z-rows
      x0 += e0 * tw[0 * 8 + q].x + e1 * tw[0 * 8 + q].y
          + e2 * tw[0 * 8 + q].z + e3 * tw[0 * 8 + q].w;
      x1 += e0 * tw[1 * 8 + q].x + e1 * tw[1 * 8 + q].y
          + e2 * tw[1 * 8 + q].z + e3 * tw[1 * 8 + q].w;
      x2 += e0 * tw[2 * 8 + q].x + e1 * tw[2 * 8 + q].y
          + e2 * tw[2 * 8 + q].z + e3 * tw[2 * 8 + q].w;
      x3 += e0 * tw[3 * 8 + q].x + e1 * tw[3 * 8 + q].y
          + e2 * tw[3 * 8 + q].z + e3 * tw[3 * 8 + q].w;
    }
    const float inv = __builtin_amdgcn_rcpf(EPS_NORM + mi * mj);
    f32x4 o;
    o.x = (x0 + bz4.x) * inv;
    o.y = (x1 + bz4.y) * inv;
    o.z = (x2 + bz4.z) * inv;
    o.w = (x3 + bz4.w) * inv;
    __builtin_nontemporal_store(o, (f32x4*)(outbase + (size_t)irow * (L * ZO)));
  };

  SPREFETCH(loA, hiA, miA, 0)

  #pragma unroll 1
  for (int i = 0; i < ICH; i += 2) {
    SWAIT(loA, hiA, miA)
    SPREFETCH(loB, hiB, miB, i + 1)
    body(loA, hiA, miA, i);
    SWAIT(loB, hiB, miB)
    const int inx = (i + 2 < ICH) ? (i + 2) : 0;
    SPREFETCH(loA, hiA, miA, inx)
    body(loB, hiB, miB, i + 1);
  }
#undef SPREFETCH
#undef SWAIT
}

// ---------------------------------------------------------------------------
extern "C" void kernel_launch(void* const* d_in, const int* in_sizes, int n_in,
                              void* d_out, int out_size, void* d_ws, size_t ws_size,
                              hipStream_t stream) {
  const float* M     = (const float*)d_in[0];
  const float* mask  = (const float*)d_in[1];
  const float* gamma = (const float*)d_in[2];
  const float* beta  = (const float*)d_in[3];
  const float* Wa    = (const float*)d_in[4];
  const float* ba    = (const float*)d_in[5];
  const float* Wb    = (const float*)d_in[6];
  const float* bb    = (const float*)d_in[7];
  const float* Wz    = (const float*)d_in[8];
  const float* bz    = (const float*)d_in[9];

  float* Z = (float*)d_out;
  float* a = (float*)d_ws;            // 512*32 f32 = 64 KB
  float* b = a + L * P;               // 64 KB
  float* T = b + L * P;               // 8 MB

  k_ln_proj<<<L / 4, 256, 0, stream>>>(M, mask, gamma, beta, Wa, ba, Wb, bb, a, b);
  k_T<<<dim3((ZO * P) / 256, L / JCH), 256, 0, stream>>>(b, Wz, T);
  k_z<<<dim3(L / 8, L / ICH), 256, 0, stream>>>(a, mask, T, bz, Z);
}

// Round 13
// 59.021 us; speedup vs baseline: 1.5833x; 1.0726x over previous
//
#include <hip/hip_runtime.h>

#define L  512
#define F  64
#define P  32
#define ZO 128
#define ICH 32   // i-chunk for k_z
#define JCH 16   // j-chunk for k_T

constexpr float EPS_LN   = 1e-10f;
constexpr float EPS_NORM = 1e-3f;

typedef float f32x2 __attribute__((ext_vector_type(2)));

// ---------------------------------------------------------------------------
// Kernel 1: LayerNorm + two 64->32 projections. (~2us, frozen)
// ---------------------------------------------------------------------------
__global__ __launch_bounds__(256) void k_ln_proj(
    const float* __restrict__ M, const float* __restrict__ mask,
    const float* __restrict__ gamma, const float* __restrict__ beta,
    const float* __restrict__ Wa, const float* __restrict__ ba,
    const float* __restrict__ Wb, const float* __restrict__ bb,
    float* __restrict__ a, float* __restrict__ b) {
  __shared__ float y_lds[4][F];
  const int wave = threadIdx.x >> 6;
  const int lane = threadIdx.x & 63;
  const int row  = blockIdx.x * 4 + wave;

  float m = M[row * F + lane];
  float s = m;
  #pragma unroll
  for (int o = 32; o >= 1; o >>= 1) s += __shfl_xor(s, o);
  float mean = s * (1.0f / F);
  float d = m - mean;
  float v = d * d;
  #pragma unroll
  for (int o = 32; o >= 1; o >>= 1) v += __shfl_xor(v, o);
  float rstd = rsqrtf(v * (1.0f / F) + EPS_LN);
  float y = d * rstd * gamma[lane] + beta[lane];
  y_lds[wave][lane] = y;
  __syncthreads();

  const float mk = mask[row];
  const float* W    = (lane < P) ? Wa : Wb;
  const float* bias = (lane < P) ? ba : bb;
  const int p = lane & (P - 1);
  float acc = 0.f;
  #pragma unroll 8
  for (int f = 0; f < F; ++f) acc += y_lds[wave][f] * W[p * F + f];
  acc = (acc + bias[p]) * mk;
  float* outp = (lane < P) ? a : b;
  outp[row * P + p] = acc;
}

// ---------------------------------------------------------------------------
// Kernel 2: T[j][z][d] = sum_e b[j][e] * Wz[z*1024 + d*32 + e]  (~5us, frozen)
// ---------------------------------------------------------------------------
__global__ __launch_bounds__(256) void k_T(
    const float* __restrict__ b, const float* __restrict__ Wz,
    float* __restrict__ T) {
  const int seg = blockIdx.x * 256 + threadIdx.x;   // 0..4095
  const int j0  = blockIdx.y * JCH;

  float4 w[8];
  const float4* wp = (const float4*)(Wz + (size_t)seg * 32);
  #pragma unroll
  for (int q = 0; q < 8; ++q) w[q] = wp[q];

  #pragma unroll 2
  for (int jj = 0; jj < JCH; ++jj) {
    const float* __restrict__ br = b + (size_t)(j0 + jj) * P;  // uniform
    float acc0 = 0.f, acc1 = 0.f, acc2 = 0.f, acc3 = 0.f;
    #pragma unroll
    for (int q = 0; q < 8; ++q) {
      acc0 += w[q].x * br[q * 4 + 0];
      acc1 += w[q].y * br[q * 4 + 1];
      acc2 += w[q].z * br[q * 4 + 2];
      acc3 += w[q].w * br[q * 4 + 3];
    }
    T[(size_t)(j0 + jj) * (ZO * P) + seg] = (acc0 + acc1) + (acc2 + acc3);
  }
}

// ---------------------------------------------------------------------------
// Kernel 3: Z[i,j,z] = (sum_d a[i,d]*T[j,z,d] + bz[z]) / (eps + mask_i*mask_j)
// Round-13: EXACT R8 structure (best measured: 58.1 total), ONE change:
// plain (L2 write-back) stores instead of nontemporal. Rationale: R9's
// direct profile (VALUBusy 28.6% at 2 waves/SIMD, 1.6 TB/s) shows waves
// stall ~70% on vmcnt waits that retire behind in-order NT store acks from
// DRAM. fillBuffer sustains 6.5 TB/s with PLAIN stores through L2 at 10%
// occupancy -- hardware full-line evictions reorder DRAM traffic better
// than our in-order NT streams, and store-acks come from L2 (fast), so the
// pipelined a-load waits stop queueing behind DRAM.
// Wave = 1 j, lane = z-pair; T fragment 16 float4 VGPRs; a-rows double-
// buffered vector loads (depth-1 pipeline); 2048 blocks.
// ---------------------------------------------------------------------------
__global__ __launch_bounds__(256) void k_z(
    const float* __restrict__ a, const float* __restrict__ mask,
    const float* __restrict__ T, const float* __restrict__ bz,
    float* __restrict__ Z) {
  const int t  = threadIdx.x;
  const int l  = t & 63;          // lane: z-pair index (z = 2l, 2l+1)
  const int jl = t >> 6;          // wave index -> j offset within block
  const int j  = blockIdx.x * 4 + jl;
  const int i0 = blockIdx.y * ICH;

  // T fragment: rows z=2l and z=2l+1 of T[j] -> 64 consecutive floats
  float4 tw[16];
  const float4* tp = (const float4*)(T + ((size_t)j * ZO + 2 * l) * P);
  #pragma unroll
  for (int q = 0; q < 16; ++q) tw[q] = tp[q];

  const float bzx = bz[2 * l], bzy = bz[2 * l + 1];
  const float mj  = mask[j];      // wave-uniform

  const float* __restrict__ abase = a + (size_t)i0 * P;
  float* outbase = Z + ((size_t)i0 * L + j) * ZO + 2 * l;

  auto body = [&](const float4* areg, int irow) {
    float x0 = 0.f, x1 = 0.f, x2 = 0.f, x3 = 0.f;
    float y0 = 0.f, y1 = 0.f, y2 = 0.f, y3 = 0.f;
    #pragma unroll
    for (int q = 0; q < 8; ++q) {
      float4 av = areg[q];
      x0 += av.x * tw[q].x;      x1 += av.y * tw[q].y;
      x2 += av.z * tw[q].z;      x3 += av.w * tw[q].w;
      y0 += av.x * tw[8 + q].x;  y1 += av.y * tw[8 + q].y;
      y2 += av.z * tw[8 + q].z;  y3 += av.w * tw[8 + q].w;
    }
    const float inv = 1.0f / (EPS_NORM + mask[i0 + irow] * mj);
    f32x2 o;
    o.x = ((x0 + x1) + (x2 + x3) + bzx) * inv;
    o.y = ((y0 + y1) + (y2 + y3) + bzy) * inv;
    *(f32x2*)(outbase + (size_t)irow * (L * ZO)) = o;   // plain store (L2)
  };

  float4 a0[8], a1[8];
  #pragma unroll
  for (int q = 0; q < 8; ++q) a0[q] = ((const float4*)abase)[q];

  for (int i = 0; i < ICH; i += 2) {
    #pragma unroll
    for (int q = 0; q < 8; ++q)
      a1[q] = ((const float4*)(abase + (size_t)(i + 1) * P))[q];
    body(a0, i);
    const int inx = (i + 2 < ICH) ? (i + 2) : 0;
    #pragma unroll
    for (int q = 0; q < 8; ++q)
      a0[q] = ((const float4*)(abase + (size_t)inx * P))[q];
    body(a1, i + 1);
  }
}

// ---------------------------------------------------------------------------
extern "C" void kernel_launch(void* const* d_in, const int* in_sizes, int n_in,
                              void* d_out, int out_size, void* d_ws, size_t ws_size,
                              hipStream_t stream) {
  const float* M     = (const float*)d_in[0];
  const float* mask  = (const float*)d_in[1];
  const float* gamma = (const float*)d_in[2];
  const float* beta  = (const float*)d_in[3];
  const float* Wa    = (const float*)d_in[4];
  const float* ba    = (const float*)d_in[5];
  const float* Wb    = (const float*)d_in[6];
  const float* bb    = (const float*)d_in[7];
  const float* Wz    = (const float*)d_in[8];
  const float* bz    = (const float*)d_in[9];

  float* Z = (float*)d_out;
  float* a = (float*)d_ws;            // 512*32 f32 = 64 KB
  float* b = a + L * P;               // 64 KB
  float* T = b + L * P;               // 8 MB

  k_ln_proj<<<L / 4, 256, 0, stream>>>(M, mask, gamma, beta, Wa, ba, Wb, bb, a, b);
  k_T<<<dim3((ZO * P) / 256, L / JCH), 256, 0, stream>>>(b, Wz, T);
  k_z<<<dim3(L / 4, L / ICH), 256, 0, stream>>>(a, mask, T, bz, Z);
}

// Round 14
// 57.023 us; speedup vs baseline: 1.6388x; 1.0350x over previous
//
#include <hip/hip_runtime.h>

#define L  512
#define F  64
#define P  32
#define ZO 128
#define ICH 32   // i-chunk for k_z
#define JCH 16   // j-chunk for k_T

constexpr float EPS_LN   = 1e-10f;
constexpr float EPS_NORM = 1e-3f;

typedef float f32x2 __attribute__((ext_vector_type(2)));
typedef float sf16  __attribute__((ext_vector_type(16)));

// ---------------------------------------------------------------------------
// Kernel 1: LayerNorm + two 64->32 projections. (~2us, frozen)
// ---------------------------------------------------------------------------
__global__ __launch_bounds__(256) void k_ln_proj(
    const float* __restrict__ M, const float* __restrict__ mask,
    const float* __restrict__ gamma, const float* __restrict__ beta,
    const float* __restrict__ Wa, const float* __restrict__ ba,
    const float* __restrict__ Wb, const float* __restrict__ bb,
    float* __restrict__ a, float* __restrict__ b) {
  __shared__ float y_lds[4][F];
  const int wave = threadIdx.x >> 6;
  const int lane = threadIdx.x & 63;
  const int row  = blockIdx.x * 4 + wave;

  float m = M[row * F + lane];
  float s = m;
  #pragma unroll
  for (int o = 32; o >= 1; o >>= 1) s += __shfl_xor(s, o);
  float mean = s * (1.0f / F);
  float d = m - mean;
  float v = d * d;
  #pragma unroll
  for (int o = 32; o >= 1; o >>= 1) v += __shfl_xor(v, o);
  float rstd = rsqrtf(v * (1.0f / F) + EPS_LN);
  float y = d * rstd * gamma[lane] + beta[lane];
  y_lds[wave][lane] = y;
  __syncthreads();

  const float mk = mask[row];
  const float* W    = (lane < P) ? Wa : Wb;
  const float* bias = (lane < P) ? ba : bb;
  const int p = lane & (P - 1);
  float acc = 0.f;
  #pragma unroll 8
  for (int f = 0; f < F; ++f) acc += y_lds[wave][f] * W[p * F + f];
  acc = (acc + bias[p]) * mk;
  float* outp = (lane < P) ? a : b;
  outp[row * P + p] = acc;
}

// ---------------------------------------------------------------------------
// Kernel 2: T[j][z][d] = sum_e b[j][e] * Wz[z*1024 + d*32 + e]  (~5us, frozen)
// ---------------------------------------------------------------------------
__global__ __launch_bounds__(256) void k_T(
    const float* __restrict__ b, const float* __restrict__ Wz,
    float* __restrict__ T) {
  const int seg = blockIdx.x * 256 + threadIdx.x;   // 0..4095
  const int j0  = blockIdx.y * JCH;

  float4 w[8];
  const float4* wp = (const float4*)(Wz + (size_t)seg * 32);
  #pragma unroll
  for (int q = 0; q < 8; ++q) w[q] = wp[q];

  #pragma unroll 2
  for (int jj = 0; jj < JCH; ++jj) {
    const float* __restrict__ br = b + (size_t)(j0 + jj) * P;  // uniform
    float acc0 = 0.f, acc1 = 0.f, acc2 = 0.f, acc3 = 0.f;
    #pragma unroll
    for (int q = 0; q < 8; ++q) {
      acc0 += w[q].x * br[q * 4 + 0];
      acc1 += w[q].y * br[q * 4 + 1];
      acc2 += w[q].z * br[q * 4 + 2];
      acc3 += w[q].w * br[q * 4 + 3];
    }
    T[(size_t)(j0 + jj) * (ZO * P) + seg] = (acc0 + acc1) + (acc2 + acc3);
  }
}

// ---------------------------------------------------------------------------
// Kernel 3: Z[i,j,z] = (sum_d a[i,d]*T[j,z,d] + bz[z]) / (eps + mask_i*mask_j)
// Round-14: R8 structure EXACTLY (NT f32x2 stores, 2048 blocks, tw[16],
// depth-1 pipeline), ONE change: a-row + mask[i] come via s_load into SGPRs
// (scalar pipe/scalar cache -> zero TA slots, zero vmcnt entries). R8's loop
// issued 9 vmem instrs per 64 FMAs (8 broadcast a-loads + mask + store) --
// ~2.1M redundant TA-issued loads of wave-uniform data; that per-CU vmem
// issue pressure is the surviving explanation of k_z's 46us vs the 21us
// write floor (R13 killed store-ack theory; R9 counters killed traffic).
// No XCD swizzle (R11's confound). vmem FIFO now carries ONLY the NT store.
// ---------------------------------------------------------------------------
__global__ __launch_bounds__(256) void k_z(
    const float* __restrict__ a, const float* __restrict__ mask,
    const float* __restrict__ T, const float* __restrict__ bz,
    float* __restrict__ Z) {
  const int t  = threadIdx.x;
  const int l  = t & 63;          // lane: z-pair index (z = 2l, 2l+1)
  const int w  = t >> 6;          // wave index -> j offset within block
  const int j  = blockIdx.x * 4 + w;
  const int i0 = blockIdx.y * ICH;

  // T fragment: rows z=2l, 2l+1 of T[j] -> 64 consecutive floats (16 float4)
  float4 tw[16];
  const float4* tp = (const float4*)(T + ((size_t)j * ZO + 2 * l) * P);
  #pragma unroll
  for (int q = 0; q < 16; ++q) tw[q] = tp[q];

  const float bzx = bz[2 * l], bzy = bz[2 * l + 1];
  const float mj  = mask[j];      // wave-uniform

  const float* abase = a + (size_t)i0 * P;   // block-uniform
  const float* mbase = mask + i0;            // block-uniform
  float* outbase = Z + ((size_t)i0 * L + j) * ZO + 2 * l;

  sf16 loA, hiA, loB, hiB;
  float miA, miB;

#define SPREFETCH(LO, HI, MI, ROW)                                         \
  {                                                                        \
    unsigned offa  = (unsigned)(ROW) * 128u;                               \
    unsigned offa2 = offa + 64u;                                           \
    unsigned offm  = (unsigned)(ROW) * 4u;                                 \
    asm volatile("s_load_dwordx16 %0, %3, %5\n\t"                          \
                 "s_load_dwordx16 %1, %3, %6\n\t"                          \
                 "s_load_dword %2, %4, %7"                                 \
                 : "=&s"(LO), "=&s"(HI), "=&s"(MI)                         \
                 : "s"(abase), "s"(mbase), "s"(offa), "s"(offa2),          \
                   "s"(offm));                                             \
  }
#define SWAIT(LO, HI, MI)                                                  \
  asm volatile("s_waitcnt lgkmcnt(0)" : "+s"(LO), "+s"(HI), "+s"(MI));

  auto body = [&](const sf16& lo, const sf16& hi, float mi, int irow) {
    float x0 = 0.f, x1 = 0.f, x2 = 0.f, x3 = 0.f;
    float y0 = 0.f, y1 = 0.f, y2 = 0.f, y3 = 0.f;
    #pragma unroll
    for (int q = 0; q < 8; ++q) {
      const float e0 = (q < 4) ? lo[4 * q + 0] : hi[4 * q - 16];
      const float e1 = (q < 4) ? lo[4 * q + 1] : hi[4 * q - 15];
      const float e2 = (q < 4) ? lo[4 * q + 2] : hi[4 * q - 14];
      const float e3 = (q < 4) ? lo[4 * q + 3] : hi[4 * q - 13];
      x0 += e0 * tw[q].x;      x1 += e1 * tw[q].y;
      x2 += e2 * tw[q].z;      x3 += e3 * tw[q].w;
      y0 += e0 * tw[8 + q].x;  y1 += e1 * tw[8 + q].y;
      y2 += e2 * tw[8 + q].z;  y3 += e3 * tw[8 + q].w;
    }
    const float inv = 1.0f / (EPS_NORM + mi * mj);
    f32x2 o;
    o.x = ((x0 + x1) + (x2 + x3) + bzx) * inv;
    o.y = ((y0 + y1) + (y2 + y3) + bzy) * inv;
    __builtin_nontemporal_store(o, (f32x2*)(outbase + (size_t)irow * (L * ZO)));
  };

  SPREFETCH(loA, hiA, miA, 0)

  #pragma unroll 1
  for (int i = 0; i < ICH; i += 2) {
    SWAIT(loA, hiA, miA)
    SPREFETCH(loB, hiB, miB, i + 1)
    body(loA, hiA, miA, i);
    SWAIT(loB, hiB, miB)
    const int inx = (i + 2 < ICH) ? (i + 2) : 0;
    SPREFETCH(loA, hiA, miA, inx)
    body(loB, hiB, miB, i + 1);
  }
#undef SPREFETCH
#undef SWAIT
}

// ---------------------------------------------------------------------------
extern "C" void kernel_launch(void* const* d_in, const int* in_sizes, int n_in,
                              void* d_out, int out_size, void* d_ws, size_t ws_size,
                              hipStream_t stream) {
  const float* M     = (const float*)d_in[0];
  const float* mask  = (const float*)d_in[1];
  const float* gamma = (const float*)d_in[2];
  const float* beta  = (const float*)d_in[3];
  const float* Wa    = (const float*)d_in[4];
  const float* ba    = (const float*)d_in[5];
  const float* Wb    = (const float*)d_in[6];
  const float* bb    = (const float*)d_in[7];
  const float* Wz    = (const float*)d_in[8];
  const float* bz    = (const float*)d_in[9];

  float* Z = (float*)d_out;
  float* a = (float*)d_ws;            // 512*32 f32 = 64 KB
  float* b = a + L * P;               // 64 KB
  float* T = b + L * P;               // 8 MB

  k_ln_proj<<<L / 4, 256, 0, stream>>>(M, mask, gamma, beta, Wa, ba, Wb, bb, a, b);
  k_T<<<dim3((ZO * P) / 256, L / JCH), 256, 0, stream>>>(b, Wz, T);
  k_z<<<dim3(L / 4, L / ICH), 256, 0, stream>>>(a, mask, T, bz, Z);
}